// Round 6
// baseline (33.616 us; speedup 1.0000x reference)
//
#include <hip/hip_runtime.h>
#include <hip/hip_fp16.h>

typedef _Float16 half8 __attribute__((ext_vector_type(8)));
typedef _Float16 half4v __attribute__((ext_vector_type(4)));
typedef float f32x4 __attribute__((ext_vector_type(4)));

__device__ __forceinline__ float leakyf(float v) { return v >= 0.f ? v : 0.7f * v; }

// Single fused kernel.
//  - Per block: build MFMA B-fragment blobs (fp16) for stacked-W [K=192][64]
//    (24 frags) and Wout [K=128][64] (16 frags) in LDS, from coalesced fp32
//    reads of W/Wout (L2-hot). Frag element (lane,j) = B[ks*32+(lane>>4)*8+j]
//    [n*16+(lane&15)], stored at frag*512 + lane*8 + j (ds_read_b128-friendly).
//  - Per wave: one 16-target tile per iteration, wave-stride loop.
//    h1 via K=192 zero-padded MFMA (type selects live 64-k band). Wave-private
//    swizzled X buffer in LDS converts C/D layout -> next A-operand layout and
//    feeds the coalesced out_h store.
__global__ __launch_bounds__(256, 2)
void shgnn_fused(const float* __restrict__ f0, const float* __restrict__ f1,
                 const float* __restrict__ f2, const float* __restrict__ W,
                 const float* __restrict__ b, const float* __restrict__ Wc,
                 const float* __restrict__ bc, const float* __restrict__ Wout,
                 const float* __restrict__ bout,
                 const int* __restrict__ tgt, const int* __restrict__ deg1,
                 const int* __restrict__ deg2,
                 int T, int per_type,
                 float* __restrict__ out_logits, float* __restrict__ out_h)
{
    __shared__ _Float16 sWF[24 * 512];   // 24KB: stacked-W B-frags
    __shared__ _Float16 sOF[16 * 512];   // 16KB: Wout B-frags
    __shared__ _Float16 sX[4][2048];     // 16KB: per-wave [row=16][ch=128] swizzled
    __shared__ float sB[192];
    __shared__ float sBC[192];
    __shared__ float sBout[64];

    const int tid = threadIdx.x;

    // ---- stage weight fragments: coalesced global read, scattered LDS write ----
    for (int i = tid; i < 3 * 64 * 64; i += 256) {          // W: i = ty*4096+k*64+col
        const int K = i >> 6, col = i & 63;                 // K = ty*64+k (0..191)
        const int ks = K >> 5, j = K & 7;
        const int lane = (((K >> 3) & 3) << 4) | (col & 15);
        const int n = (col >> 4) & 3;
        sWF[((ks * 4 + n) << 9) + (lane << 3) + j] = (_Float16)W[i];
    }
    for (int i = tid; i < 128 * 64; i += 256) {             // Wout: i = k*64+col
        const int K = i >> 6, col = i & 63;
        const int ks = K >> 5, j = K & 7;
        const int lane = (((K >> 3) & 3) << 4) | (col & 15);
        const int n = col >> 4;
        sOF[((ks * 4 + n) << 9) + (lane << 3) + j] = (_Float16)Wout[i];
    }
    if (tid < 192) sB[tid] = b[tid];
    if (tid < 192) sBC[tid] = bc[tid];
    if (tid < 64)  sBout[tid] = bout[tid];
    __syncthreads();

    const int lane = tid & 63;
    const int l15 = lane & 15;
    const int lq  = lane >> 4;
    char* const sXw = (char*)sX[tid >> 6];

    const int ntiles = (T + 15) >> 4;
    const int gwave = blockIdx.x * 4 + (tid >> 6);
    const int nwaves = gridDim.x * 4;

    for (int tile = gwave; tile < ntiles; tile += nwaves) {
        // lane (mod 16) owns tile row l15
        int t = tile * 16 + l15;
        if (t >= T) t = T - 1;                       // duplicate rows write same value
        const int nnv = tgt[t];                      // coalesced 64B per wave
        const int tyv = (nnv >= 2 * per_type) ? 2 : (nnv >= per_type ? 1 : 0);
        const int d1v = deg1[nnv];
        const int d2v = deg2[nnv];

        // ---- A fragments from f-row (fp32 -> fp16 RNE) ----
        const float* fb = (tyv == 0) ? f0 : ((tyv == 1) ? f1 : f2);
        const float* frp = fb + (size_t)(nnv - tyv * per_type) * 64 + (lq << 3);
        const f32x4 a00 = *(const f32x4*)frp;
        const f32x4 a01 = *(const f32x4*)(frp + 4);
        const f32x4 a10 = *(const f32x4*)(frp + 32);
        const f32x4 a11 = *(const f32x4*)(frp + 36);
        const half8 a0 = {(_Float16)a00.x, (_Float16)a00.y, (_Float16)a00.z, (_Float16)a00.w,
                          (_Float16)a01.x, (_Float16)a01.y, (_Float16)a01.z, (_Float16)a01.w};
        const half8 a1 = {(_Float16)a10.x, (_Float16)a10.y, (_Float16)a10.z, (_Float16)a10.w,
                          (_Float16)a11.x, (_Float16)a11.y, (_Float16)a11.z, (_Float16)a11.w};
        const half8 z8 = {(_Float16)0.f, (_Float16)0.f, (_Float16)0.f, (_Float16)0.f,
                          (_Float16)0.f, (_Float16)0.f, (_Float16)0.f, (_Float16)0.f};
        const int k0 = 2 * tyv, k1 = 2 * tyv + 1;    // live k-slices in stacked K

        // per-row types for bias lookup (rows 0..15 held by lanes 0..15)
        int tyr[4];
        #pragma unroll
        for (int r = 0; r < 4; ++r) tyr[r] = __shfl(tyv, (lq << 2) + r);

        // ---- h1 = leaky(F~ @ Wstacked + b[ty_row]) : 24 MFMA -> X[.., 0..63] ----
        #pragma unroll
        for (int n = 0; n < 4; ++n) {
            f32x4 acc = {0.f, 0.f, 0.f, 0.f};
            #pragma unroll
            for (int ks = 0; ks < 6; ++ks) {
                const half8 av = (ks == k0) ? a0 : ((ks == k1) ? a1 : z8);
                const half8 wb = *(const half8*)__builtin_assume_aligned(
                    (sWF + (ks * 4 + n) * 512 + lane * 8), 16);
                acc = __builtin_amdgcn_mfma_f32_16x16x32_f16(av, wb, acc, 0, 0, 0);
            }
            #pragma unroll
            for (int r = 0; r < 4; ++r) {
                const int row = (lq << 2) + r;               // C/D: row=(lane>>4)*4+reg
                const float v = leakyf(acc[r] + sB[tyr[r] * 64 + n * 16 + l15]);
                const int off = (row * 256 + (n * 16 + l15) * 2) ^ ((row & 7) << 4);
                *(_Float16*)(sXw + off) = (_Float16)v;       // RNE, matches astype(f16)
            }
        }

        // ---- h2 = leaky(Wc[ty][d1] + Wc[ty][100+d2] + bc[ty]) -> X[.., 64..127] ----
        {
            const int cb = lq << 4;                          // 16 ch per lane
            const float* wcb = Wc + (size_t)tyv * 12800;
            const float* q1 = wcb + (size_t)d1v * 64 + cb;
            const float* q2 = wcb + (size_t)(100 + d2v) * 64 + cb;
            const float* qb = &sBC[tyv * 64 + cb];
            #pragma unroll
            for (int q = 0; q < 4; ++q) {
                const f32x4 u  = *(const f32x4*)(q1 + q * 4);
                const f32x4 w2 = *(const f32x4*)(q2 + q * 4);
                const f32x4 bb = *(const f32x4*)(qb + q * 4);
                half4v hv;
                #pragma unroll
                for (int j = 0; j < 4; ++j)
                    hv[j] = (_Float16)leakyf(u[j] + w2[j] + bb[j]);
                const int off = (l15 * 256 + 128 + cb * 2 + q * 8) ^ ((l15 & 7) << 4);
                *(half4v*)__builtin_assume_aligned((sXw + off), 8) = hv;
            }
        }

        // ---- logits = X @ Wout + bout : 16 MFMA ----
        half8 xa[4];
        #pragma unroll
        for (int ks = 0; ks < 4; ++ks) {
            const int off = (l15 * 256 + ks * 64 + (lq << 4)) ^ ((l15 & 7) << 4);
            xa[ks] = *(const half8*)__builtin_assume_aligned((sXw + off), 16);
        }
        #pragma unroll
        for (int n = 0; n < 4; ++n) {
            const float bo = (float)(_Float16)sBout[n * 16 + l15];
            f32x4 acc = {bo, bo, bo, bo};
            #pragma unroll
            for (int ks = 0; ks < 4; ++ks) {
                const half8 wf = *(const half8*)__builtin_assume_aligned(
                    (sOF + (ks * 4 + n) * 512 + lane * 8), 16);
                acc = __builtin_amdgcn_mfma_f32_16x16x32_f16(xa[ks], wf, acc, 0, 0, 0);
            }
            #pragma unroll
            for (int r = 0; r < 4; ++r) {
                int trr = tile * 16 + (lq << 2) + r;
                if (trr >= T) trr = T - 1;                   // duplicate row, same value
                out_logits[(size_t)trr * 64 + n * 16 + l15] = (float)(_Float16)acc[r];
            }
        }

        // ---- out_h: coalesced fp32 store from X ----
        {
            const int rh = lane >> 2;
            int tb = tile * 16 + rh;
            if (tb >= T) tb = T - 1;
            const int cb2 = (lane & 3) << 5;                 // 32 halves per lane
            float* op = out_h + (size_t)tb * 128 + cb2;
            #pragma unroll
            for (int p = 0; p < 4; ++p) {
                const int off = (rh * 256 + cb2 * 2 + p * 16) ^ ((rh & 7) << 4);
                const half8 hv = *(const half8*)__builtin_assume_aligned((sXw + off), 16);
                f32x4 o0 = {(float)hv[0], (float)hv[1], (float)hv[2], (float)hv[3]};
                f32x4 o1 = {(float)hv[4], (float)hv[5], (float)hv[6], (float)hv[7]};
                *(f32x4*)(op + p * 8) = o0;
                *(f32x4*)(op + p * 8 + 4) = o1;
            }
        }
    }
}

extern "C" void kernel_launch(void* const* d_in, const int* in_sizes, int n_in,
                              void* d_out, int out_size, void* d_ws, size_t ws_size,
                              hipStream_t stream) {
    const float* f0   = (const float*)d_in[0];
    const float* f1   = (const float*)d_in[1];
    const float* f2   = (const float*)d_in[2];
    const float* W    = (const float*)d_in[3];
    const float* b    = (const float*)d_in[4];
    const float* Wc   = (const float*)d_in[5];
    const float* bc   = (const float*)d_in[6];
    const float* Wout = (const float*)d_in[7];
    const float* bout = (const float*)d_in[8];
    const int* deg1   = (const int*)d_in[10];
    const int* deg2   = (const int*)d_in[11];
    const int* tgt    = (const int*)d_in[12];

    const int T = in_sizes[12];
    const int per_type = in_sizes[0] / 64;

    float* out_logits = (float*)d_out;
    float* out_h = out_logits + (size_t)T * 64;

    const int ntiles = (T + 15) / 16;
    int blocks = 512;                          // 2 blocks/CU resident, persistent
    const int need = (ntiles + 3) / 4;
    if (need < blocks) blocks = need;

    shgnn_fused<<<dim3(blocks), dim3(256), 0, stream>>>(
        f0, f1, f2, W, b, Wc, bc, Wout, bout,
        tgt, deg1, deg2, T, per_type, out_logits, out_h);
}

// Round 7
// 32.021 us; speedup vs baseline: 1.0498x; 1.0498x over previous
//
#include <hip/hip_runtime.h>
#include <hip/hip_fp16.h>

typedef _Float16 half8 __attribute__((ext_vector_type(8)));
typedef _Float16 half2v __attribute__((ext_vector_type(2)));
typedef float f32x2 __attribute__((ext_vector_type(2)));
typedef float f32x4 __attribute__((ext_vector_type(4)));

__device__ __forceinline__ float leakyf(float v) { return v >= 0.f ? v : 0.7f * v; }

// ---------------- pass 1: bucket targets by node type, store (t, n) --------
__global__ void bucket_kernel(const int* __restrict__ tgt, int T, int per_type,
                              int* __restrict__ counters, int2* __restrict__ lists, int cap)
{
    __shared__ int scnt[3];
    __shared__ int sbase[3];
    const int tid = threadIdx.x;
    if (tid < 3) scnt[tid] = 0;
    __syncthreads();
    const int t = blockIdx.x * blockDim.x + tid;
    int ty = 0, pos = 0, n = 0;
    if (t < T) {
        n = tgt[t];
        ty = (n >= 2 * per_type) ? 2 : (n >= per_type ? 1 : 0);
        pos = atomicAdd(&scnt[ty], 1);
    }
    __syncthreads();
    if (tid < 3) sbase[tid] = atomicAdd(&counters[tid], scnt[tid]);
    __syncthreads();
    if (t < T) lists[ty * cap + sbase[ty] + pos] = make_int2(t, n);
}

// ---------------- pass 2: type-uniform 16-target tiles, coalesced I/O ------
__global__ __launch_bounds__(512, 4)
void shgnn_main2(const float* __restrict__ f0, const float* __restrict__ f1,
                 const float* __restrict__ f2, const float* __restrict__ W,
                 const float* __restrict__ b, const float* __restrict__ Wc,
                 const float* __restrict__ bc, const float* __restrict__ Wout,
                 const float* __restrict__ bout,
                 const int* __restrict__ deg1, const int* __restrict__ deg2,
                 const int* __restrict__ counters, const int2* __restrict__ lists,
                 int cap, int per_type,
                 float* __restrict__ out_logits, float* __restrict__ out_h)
{
    __shared__ _Float16 sWF[24 * 512];   // 24KB: W B-frags [ty][ks][n]
    __shared__ _Float16 sOF[16 * 512];   // 16KB: Wout B-frags [ks][n]
    __shared__ _Float16 sX[8][2048];     // 32KB: per-wave [row=16][ch=128] swizzled
    __shared__ float sB[192];
    __shared__ float sBC[192];
    __shared__ float sBout[64];

    const int tid = threadIdx.x;

    // stage weight fragments (coalesced global fp32 reads, scattered b16 LDS writes)
    for (int i = tid; i < 3 * 64 * 64; i += 512) {         // i = ty*4096 + k*64 + col
        const int k6 = i >> 6, col = i & 63;
        const int ty = k6 >> 6, k = k6 & 63;
        const int ks = k >> 5, j = k & 7;
        const int ln = (((k >> 3) & 3) << 4) | (col & 15);
        const int n = col >> 4;
        sWF[((ty * 8 + ks * 4 + n) << 9) + (ln << 3) + j] = (_Float16)W[i];
    }
    for (int i = tid; i < 128 * 64; i += 512) {            // i = k*64 + col
        const int k = i >> 6, col = i & 63;
        const int ks = k >> 5, j = k & 7;
        const int ln = (((k >> 3) & 3) << 4) | (col & 15);
        const int n = col >> 4;
        sOF[((ks * 4 + n) << 9) + (ln << 3) + j] = (_Float16)Wout[i];
    }
    if (tid < 192) sB[tid] = b[tid];
    if (tid < 192) sBC[tid] = bc[tid];
    if (tid < 64)  sBout[tid] = bout[tid];
    __syncthreads();

    const int lane = tid & 63;
    const int l15 = lane & 15;
    const int lq  = lane >> 4;
    char* const sXw = (char*)sX[tid >> 6];

    const int c0 = counters[0], c1 = counters[1], c2 = counters[2];
    const int g0 = (c0 + 15) >> 4, g1 = (c1 + 15) >> 4, g2 = (c2 + 15) >> 4;
    const int ng = g0 + g1 + g2;

    const int gwave = blockIdx.x * 8 + (tid >> 6);
    const int nwaves = gridDim.x * 8;

    for (int g = gwave; g < ng; g += nwaves) {
        int ty, gi, cnt;
        if (g < g0)           { ty = 0; gi = g;           cnt = c0; }
        else if (g < g0 + g1) { ty = 1; gi = g - g0;      cnt = c1; }
        else                  { ty = 2; gi = g - g0 - g1; cnt = c2; }
        const int base = gi << 4;
        int idx = base + l15;
        if (idx >= cnt) idx = cnt - 1;               // duplicate rows, same values
        const int2 e = lists[ty * cap + idx];        // coalesced 128B
        const int tvv = e.x;
        const int nnv = e.y;

        const float* fb = (ty == 0) ? f0 : ((ty == 1) ? f1 : f2);
        const float* wcb = Wc + (size_t)ty * 12800;
        const float bcv = sBC[ty * 64 + lane];

        // ---- phase A: per-row coalesced staging (lane = channel) ----
        #pragma unroll
        for (int r = 0; r < 16; ++r) {
            const int nr = __builtin_amdgcn_readlane(nnv, r);     // SGPR
            const float fv = fb[(size_t)(nr - ty * per_type) * 64 + lane];
            const int d1r = deg1[nr];                             // scalar load
            const int d2r = deg2[nr];
            const float h2 = leakyf(wcb[d1r * 64 + lane] + wcb[(100 + d2r) * 64 + lane] + bcv);
            const int swr = (r & 7) << 4;
            *(_Float16*)(sXw + ((r * 256 + lane * 2) ^ swr))       = (_Float16)fv;
            *(_Float16*)(sXw + ((r * 256 + 128 + lane * 2) ^ swr)) = (_Float16)h2;
        }

        // ---- A-frags for h1 from X[.., 0..63] (consumed before overwrite) ----
        const int swl = (l15 & 7) << 4;
        const half8 a0 = *(const half8*)(sXw + ((l15 * 256 + lq * 16) ^ swl));
        const half8 a1 = *(const half8*)(sXw + ((l15 * 256 + 64 + lq * 16) ^ swl));

        // ---- h1 = leaky(F @ W[ty] + b[ty]) : 8 MFMA -> X[.., 0..63] ----
        #pragma unroll
        for (int n = 0; n < 4; ++n) {
            const float bn = sB[ty * 64 + n * 16 + l15];
            f32x4 acc = {bn, bn, bn, bn};
            const half8 wb0 = *(const half8*)(sWF + ((ty * 8 + 0 * 4 + n) << 9) + lane * 8);
            const half8 wb1 = *(const half8*)(sWF + ((ty * 8 + 1 * 4 + n) << 9) + lane * 8);
            acc = __builtin_amdgcn_mfma_f32_16x16x32_f16(a0, wb0, acc, 0, 0, 0);
            acc = __builtin_amdgcn_mfma_f32_16x16x32_f16(a1, wb1, acc, 0, 0, 0);
            #pragma unroll
            for (int r = 0; r < 4; ++r) {
                const int row = (lq << 2) + r;               // C/D: row=(lane>>4)*4+reg
                const float v = leakyf(acc[r]);
                const int off = (row * 256 + (n * 16 + l15) * 2) ^ ((row & 7) << 4);
                *(_Float16*)(sXw + off) = (_Float16)v;       // RNE, matches astype(f16)
            }
        }

        // ---- logits = X @ Wout + bout : 16 MFMA ----
        half8 xa[4];
        #pragma unroll
        for (int ks = 0; ks < 4; ++ks)
            xa[ks] = *(const half8*)(sXw + ((l15 * 256 + ks * 64 + lq * 16) ^ swl));

        int tr4[4];
        #pragma unroll
        for (int r = 0; r < 4; ++r) tr4[r] = __shfl(tvv, (lq << 2) + r);

        #pragma unroll
        for (int n = 0; n < 4; ++n) {
            const float bo = (float)(_Float16)sBout[n * 16 + l15];
            f32x4 acc = {bo, bo, bo, bo};
            #pragma unroll
            for (int ks = 0; ks < 4; ++ks) {
                const half8 wf = *(const half8*)(sOF + ((ks * 4 + n) << 9) + lane * 8);
                acc = __builtin_amdgcn_mfma_f32_16x16x32_f16(xa[ks], wf, acc, 0, 0, 0);
            }
            #pragma unroll
            for (int r = 0; r < 4; ++r) {
                out_logits[(size_t)tr4[r] * 64 + n * 16 + l15] = (float)(_Float16)acc[r];
            }
        }

        // ---- out_h: per-row coalesced fp32 store (lane = channel pair) ----
        #pragma unroll
        for (int r = 0; r < 16; ++r) {
            const int tb = __builtin_amdgcn_readlane(tvv, r);    // SGPR
            const half2v hv = *(const half2v*)(sXw + ((r * 256 + lane * 4) ^ ((r & 7) << 4)));
            f32x2 o = {(float)hv.x, (float)hv.y};
            *(f32x2*)(out_h + (size_t)tb * 128 + lane * 2) = o;
        }
    }
}

// ---------------- fallback (R1 kernel) if ws too small ----------------------
__global__ __launch_bounds__(512, 2)
void shgnn_fallback(const float* __restrict__ f0, const float* __restrict__ f1,
                    const float* __restrict__ f2, const float* __restrict__ W,
                    const float* __restrict__ b, const float* __restrict__ Wc,
                    const float* __restrict__ bc, const float* __restrict__ Wout,
                    const float* __restrict__ bout, const int* __restrict__ type_mask,
                    const int* __restrict__ deg1, const int* __restrict__ deg2,
                    const int* __restrict__ tgt, int T, int per_type,
                    float* __restrict__ out_logits, float* __restrict__ out_h)
{
    __shared__ float  sW[3 * 64 * 64];
    __shared__ __half sWout[2 * 64 * 64];
    const int tid = threadIdx.x;
    {
        const float4* src = reinterpret_cast<const float4*>(W);
        float4* dst = reinterpret_cast<float4*>(sW);
        for (int i = tid; i < 3 * 64 * 64 / 4; i += 512) dst[i] = src[i];
        for (int i = tid; i < 2 * 64 * 64; i += 512) sWout[i] = __float2half(Wout[i]);
    }
    __syncthreads();
    const int lane = tid & 63;
    const int wid  = tid >> 6;
    const float b_l0 = b[lane], b_l1 = b[64 + lane], b_l2 = b[128 + lane];
    const float bc_l0 = bc[lane], bc_l1 = bc[64 + lane], bc_l2 = bc[128 + lane];
    const float bout_l = __half2float(__float2half(bout[lane]));
    const int gw = blockIdx.x * 8 + wid;
    const int gstride = gridDim.x * 8;
    for (int t = gw; t < T; t += gstride) {
        const int n  = tgt[t];
        const int ty = type_mask[n];
        const int p  = n - ty * per_type;
        const float* f = (ty == 0 ? f0 : (ty == 1 ? f1 : f2)) + (size_t)p * 64;
        const float fv = f[lane];
        float acc = (ty == 0 ? b_l0 : (ty == 1 ? b_l1 : b_l2));
        const float* w = sW + ty * 4096;
        #pragma unroll
        for (int k = 0; k < 64; ++k) {
            const float fk = __uint_as_float(
                __builtin_amdgcn_readlane(__float_as_uint(fv), k));
            acc = fmaf(fk, w[k * 64 + lane], acc);
        }
        acc = (acc >= 0.f) ? acc : 0.7f * acc;
        const int d1 = deg1[n], d2 = deg2[n];
        const float* wc = Wc + (size_t)ty * 12800;
        float acc2 = (ty == 0 ? bc_l0 : (ty == 1 ? bc_l1 : bc_l2))
                   + wc[d1 * 64 + lane] + wc[(100 + d2) * 64 + lane];
        acc2 = (acc2 >= 0.f) ? acc2 : 0.7f * acc2;
        const float x1 = __half2float(__float2half(acc));
        const float x2 = __half2float(__float2half(acc2));
        float lg = bout_l;
        #pragma unroll
        for (int k = 0; k < 64; ++k) {
            const float xk = __uint_as_float(
                __builtin_amdgcn_readlane(__float_as_uint(x1), k));
            lg = fmaf(xk, __half2float(sWout[k * 64 + lane]), lg);
        }
        #pragma unroll
        for (int k = 0; k < 64; ++k) {
            const float xk = __uint_as_float(
                __builtin_amdgcn_readlane(__float_as_uint(x2), k));
            lg = fmaf(xk, __half2float(sWout[(64 + k) * 64 + lane]), lg);
        }
        lg = __half2float(__float2half(lg));
        out_logits[(size_t)t * 64 + lane] = lg;
        out_h[(size_t)t * 128 + lane]      = x1;
        out_h[(size_t)t * 128 + 64 + lane] = x2;
    }
}

extern "C" void kernel_launch(void* const* d_in, const int* in_sizes, int n_in,
                              void* d_out, int out_size, void* d_ws, size_t ws_size,
                              hipStream_t stream) {
    const float* f0   = (const float*)d_in[0];
    const float* f1   = (const float*)d_in[1];
    const float* f2   = (const float*)d_in[2];
    const float* W    = (const float*)d_in[3];
    const float* b    = (const float*)d_in[4];
    const float* Wc   = (const float*)d_in[5];
    const float* bc   = (const float*)d_in[6];
    const float* Wout = (const float*)d_in[7];
    const float* bout = (const float*)d_in[8];
    const int* type_mask = (const int*)d_in[9];
    const int* deg1   = (const int*)d_in[10];
    const int* deg2   = (const int*)d_in[11];
    const int* tgt    = (const int*)d_in[12];

    const int T = in_sizes[12];
    const int per_type = in_sizes[0] / 64;

    float* out_logits = (float*)d_out;
    float* out_h = out_logits + (size_t)T * 64;

    const size_t ws_needed = 16 * sizeof(int) + (size_t)3 * T * sizeof(int2);
    if (ws_size >= ws_needed) {
        int* counters = (int*)d_ws;
        int2* lists   = (int2*)(counters + 16);
        (void)hipMemsetAsync(counters, 0, 16 * sizeof(int), stream);
        bucket_kernel<<<dim3((T + 255) / 256), dim3(256), 0, stream>>>(
            tgt, T, per_type, counters, lists, T);

        const int max_tiles = (T + 15) / 16 + 3;
        int blocks = (max_tiles + 7) / 8;
        if (blocks > 512) blocks = 512;
        shgnn_main2<<<dim3(blocks), dim3(512), 0, stream>>>(
            f0, f1, f2, W, b, Wc, bc, Wout, bout,
            deg1, deg2, counters, lists, T, per_type,
            out_logits, out_h);
    } else {
        int blocks = (T + 7) / 8;
        if (blocks > 512) blocks = 512;
        shgnn_fallback<<<dim3(blocks), dim3(512), 0, stream>>>(
            f0, f1, f2, W, b, Wc, bc, Wout, bout,
            type_mask, deg1, deg2, tgt, T, per_type,
            out_logits, out_h);
    }
}

// Round 8
// 23.939 us; speedup vs baseline: 1.4043x; 1.3376x over previous
//
#include <hip/hip_runtime.h>
#include <hip/hip_fp16.h>

typedef _Float16 half8 __attribute__((ext_vector_type(8)));
typedef _Float16 half2v __attribute__((ext_vector_type(2)));
typedef float f32x2 __attribute__((ext_vector_type(2)));
typedef float f32x4 __attribute__((ext_vector_type(4)));

__device__ __forceinline__ float leakyf(float v) { return v >= 0.f ? v : 0.7f * v; }

// Single fused kernel, one dispatch.
//  - t-consecutive 16-target tiles (streaming output writes), one tile/wave.
//  - Mixed node types inside a tile via K=192 stacked-W MFMA: lane's A-frag
//    occupies the 64-wide k-band of its row's type; other bands are zero.
//  - Phase A: per-row readlane->SGPR staging; f-row & Wc rows are uniform-base
//    coalesced vector loads, deg1/deg2 scalar loads. Rows land in the wave's
//    swizzled X LDS buffer, which also converts MFMA C/D layout -> A layout
//    and feeds streaming out_h stores.
__global__ __launch_bounds__(512, 4)
void shgnn_fused2(const float* __restrict__ f0, const float* __restrict__ f1,
                  const float* __restrict__ f2, const float* __restrict__ W,
                  const float* __restrict__ b, const float* __restrict__ Wc,
                  const float* __restrict__ bc, const float* __restrict__ Wout,
                  const float* __restrict__ bout,
                  const int* __restrict__ tgt, const int* __restrict__ deg1,
                  const int* __restrict__ deg2,
                  int T, int per_type,
                  float* __restrict__ out_logits, float* __restrict__ out_h)
{
    __shared__ _Float16 sWF[24 * 512];   // 24KB: stacked-W B-frags [ks=0..5][n=0..3]
    __shared__ _Float16 sOF[16 * 512];   // 16KB: Wout B-frags [ks=0..3][n=0..3]
    __shared__ _Float16 sX[8][2048];     // 32KB: per-wave [row=16][ch=128] swizzled
    __shared__ float sB[192];
    __shared__ float sBC[192];
    __shared__ float sBout[64];

    const int tid = threadIdx.x;

    // ---- stage weight fragments (coalesced fp32 reads, scattered b16 writes) ----
    for (int i = tid; i < 3 * 64 * 64; i += 512) {         // i = K*64 + col, K=ty*64+k
        const int K = i >> 6, col = i & 63;
        const int ks = K >> 5, j = K & 7;
        const int ln = (((K >> 3) & 3) << 4) | (col & 15);
        const int n = col >> 4;
        sWF[((ks * 4 + n) << 9) + (ln << 3) + j] = (_Float16)W[i];
    }
    for (int i = tid; i < 128 * 64; i += 512) {            // i = k*64 + col
        const int k = i >> 6, col = i & 63;
        const int ks = k >> 5, j = k & 7;
        const int ln = (((k >> 3) & 3) << 4) | (col & 15);
        const int n = col >> 4;
        sOF[((ks * 4 + n) << 9) + (ln << 3) + j] = (_Float16)Wout[i];
    }
    if (tid < 192) sB[tid] = b[tid];
    if (tid < 192) sBC[tid] = bc[tid];
    if (tid < 64)  sBout[tid] = bout[tid];
    __syncthreads();

    const int lane = tid & 63;
    const int l15 = lane & 15;
    const int lq  = lane >> 4;
    char* const sXw = (char*)sX[tid >> 6];

    const int ntiles = (T + 15) >> 4;
    const int gwave = blockIdx.x * 8 + (tid >> 6);
    const int nwaves = gridDim.x * 8;

    for (int tile = gwave; tile < ntiles; tile += nwaves) {
        int t = tile * 16 + l15;
        if (t >= T) t = T - 1;                        // tail rows duplicate (T%16==0: unused)
        const int nnv = tgt[t];                       // coalesced 64B
        const int tyv = (nnv >= 2 * per_type) ? 2 : (nnv >= per_type ? 1 : 0);

        // ---- phase A: per-row coalesced staging (lane = channel) ----
        #pragma unroll
        for (int r = 0; r < 16; ++r) {
            const int nr = __builtin_amdgcn_readlane(nnv, r);          // SGPR
            const int tyr = (nr >= 2 * per_type) ? 2 : (nr >= per_type ? 1 : 0);
            const float* fbr = (tyr == 0) ? f0 : ((tyr == 1) ? f1 : f2);
            const float fv = fbr[(size_t)(nr - tyr * per_type) * 64 + lane];
            const int d1r = deg1[nr];                                  // scalar loads
            const int d2r = deg2[nr];
            const float* wcb = Wc + (size_t)tyr * 12800;
            const float h2 = leakyf(wcb[d1r * 64 + lane] + wcb[(100 + d2r) * 64 + lane]
                                    + sBC[tyr * 64 + lane]);
            const int swr = (r & 7) << 4;
            *(_Float16*)(sXw + ((r * 256 + lane * 2) ^ swr))       = (_Float16)fv;
            *(_Float16*)(sXw + ((r * 256 + 128 + lane * 2) ^ swr)) = (_Float16)h2;
        }

        // ---- A-frags for h1 from X[.., 0..63] (consumed before overwrite) ----
        const int swl = (l15 & 7) << 4;
        const half8 a0 = *(const half8*)(sXw + ((l15 * 256 + lq * 16) ^ swl));
        const half8 a1 = *(const half8*)(sXw + ((l15 * 256 + 64 + lq * 16) ^ swl));
        const half8 z8 = {(_Float16)0.f, (_Float16)0.f, (_Float16)0.f, (_Float16)0.f,
                          (_Float16)0.f, (_Float16)0.f, (_Float16)0.f, (_Float16)0.f};
        const int k0 = 2 * tyv, k1 = 2 * tyv + 1;     // live k-slices (per-lane)

        int tyr4[4];
        #pragma unroll
        for (int r = 0; r < 4; ++r) tyr4[r] = __shfl(tyv, (lq << 2) + r);

        // ---- h1 = leaky(F~ @ Wstacked + b[ty_row]) : 24 MFMA -> X[.., 0..63] ----
        #pragma unroll
        for (int n = 0; n < 4; ++n) {
            f32x4 acc = {0.f, 0.f, 0.f, 0.f};
            #pragma unroll
            for (int ks = 0; ks < 6; ++ks) {
                const half8 av = (ks == k0) ? a0 : ((ks == k1) ? a1 : z8);
                const half8 wb = *(const half8*)(sWF + ((ks * 4 + n) << 9) + lane * 8);
                acc = __builtin_amdgcn_mfma_f32_16x16x32_f16(av, wb, acc, 0, 0, 0);
            }
            #pragma unroll
            for (int r = 0; r < 4; ++r) {
                const int row = (lq << 2) + r;                // C/D: row=(lane>>4)*4+reg
                const float v = leakyf(acc[r] + sB[tyr4[r] * 64 + n * 16 + l15]);
                const int off = (row * 256 + (n * 16 + l15) * 2) ^ ((row & 7) << 4);
                *(_Float16*)(sXw + off) = (_Float16)v;        // RNE, matches astype(f16)
            }
        }

        // ---- logits = X @ Wout + bout : 16 MFMA ----
        half8 xa[4];
        #pragma unroll
        for (int ks = 0; ks < 4; ++ks)
            xa[ks] = *(const half8*)(sXw + ((l15 * 256 + ks * 64 + lq * 16) ^ swl));

        #pragma unroll
        for (int n = 0; n < 4; ++n) {
            const float bo = (float)(_Float16)sBout[n * 16 + l15];
            f32x4 acc = {bo, bo, bo, bo};
            #pragma unroll
            for (int ks = 0; ks < 4; ++ks) {
                const half8 wf = *(const half8*)(sOF + ((ks * 4 + n) << 9) + lane * 8);
                acc = __builtin_amdgcn_mfma_f32_16x16x32_f16(xa[ks], wf, acc, 0, 0, 0);
            }
            #pragma unroll
            for (int r = 0; r < 4; ++r) {
                int trr = tile * 16 + (lq << 2) + r;
                if (trr >= T) trr = T - 1;
                out_logits[(size_t)trr * 64 + n * 16 + l15] = (float)(_Float16)acc[r];
            }
        }

        // ---- out_h: per-row streaming fp32 store (rows consecutive) ----
        #pragma unroll
        for (int r = 0; r < 16; ++r) {
            int tb = tile * 16 + r;
            if (tb >= T) tb = T - 1;
            const half2v hv = *(const half2v*)(sXw + ((r * 256 + lane * 4) ^ ((r & 7) << 4)));
            f32x2 o = {(float)hv.x, (float)hv.y};
            *(f32x2*)(out_h + (size_t)tb * 128 + lane * 2) = o;
        }
    }
}

extern "C" void kernel_launch(void* const* d_in, const int* in_sizes, int n_in,
                              void* d_out, int out_size, void* d_ws, size_t ws_size,
                              hipStream_t stream) {
    const float* f0   = (const float*)d_in[0];
    const float* f1   = (const float*)d_in[1];
    const float* f2   = (const float*)d_in[2];
    const float* W    = (const float*)d_in[3];
    const float* b    = (const float*)d_in[4];
    const float* Wc   = (const float*)d_in[5];
    const float* bc   = (const float*)d_in[6];
    const float* Wout = (const float*)d_in[7];
    const float* bout = (const float*)d_in[8];
    const int* deg1   = (const int*)d_in[10];
    const int* deg2   = (const int*)d_in[11];
    const int* tgt    = (const int*)d_in[12];

    const int T = in_sizes[12];
    const int per_type = in_sizes[0] / 64;

    float* out_logits = (float*)d_out;
    float* out_h = out_logits + (size_t)T * 64;

    const int ntiles = (T + 15) / 16;
    int blocks = (ntiles + 7) / 8;       // 8 waves/block, 1 tile/wave
    if (blocks > 512) blocks = 512;      // 2 blocks/CU resident (74KB LDS)

    shgnn_fused2<<<dim3(blocks), dim3(512), 0, stream>>>(
        f0, f1, f2, W, b, Wc, bc, Wout, bout,
        tgt, deg1, deg2, T, per_type, out_logits, out_h);
}